// Round 1
// baseline (1450.254 us; speedup 1.0000x reference)
//
#include <hip/hip_runtime.h>
#include <hip/hip_bf16.h>

#define N_NODES 4096
#define E_EDGES 131072
#define DIN_    512
#define DM_     256
#define DFF_    2048
#define EPS_    1e-5f

// ---------------------------------------------------------------------------
// Generic fp32 tiled GEMM: C[m,n] = epi(alpha * sum_k A[m,k]*B(k,n) + bias[n])
//   BT=true : B row-major [N,K]  -> B(k,n) = B[n*ldb + k]   (PyTorch W.T style)
//   BT=false: B row-major [K,N]  -> B(k,n) = B[k*ldb + n]
//   SPLITK  : gridDim.z partitions K in chunks of `kchunk`; atomicAdd outputs;
//             bias added only by blockIdx.z==0 (output must be zeroed first).
// Tiles: 64x64, BK=16, 256 threads, 4x4 accum per thread.
// ---------------------------------------------------------------------------
template<bool BT, bool RELU, bool SPLITK>
__global__ __launch_bounds__(256)
void gemm_kernel(const float* __restrict__ A, const float* __restrict__ B,
                 const float* __restrict__ bias, float* __restrict__ C,
                 int M, int Nn, int K, int lda, int ldb, int ldc,
                 float alpha, int kchunk)
{
    __shared__ float As[16][68];
    __shared__ float Bs[16][68];
    const int tid = threadIdx.x;
    const int tx = tid & 15, ty = tid >> 4;
    const int bm = blockIdx.y * 64, bn = blockIdx.x * 64;
    int k0 = 0, k1 = K;
    if (SPLITK) {
        k0 = blockIdx.z * kchunk;
        k1 = k0 + kchunk; if (k1 > K) k1 = K;
    }
    float acc[4][4] = {};
    for (int kb = k0; kb < k1; kb += 16) {
        #pragma unroll
        for (int i = 0; i < 4; ++i) {            // A tile 64x16 -> As[k][m]
            int e = tid + i * 256;
            int r = e >> 4, c = e & 15;
            int gr = bm + r, gc = kb + c;
            float v = (gr < M && gc < K) ? A[(size_t)gr * lda + gc] : 0.f;
            As[c][r] = v;
        }
        #pragma unroll
        for (int i = 0; i < 4; ++i) {            // B tile -> Bs[k][n]
            int e = tid + i * 256;
            if (BT) {
                int r = e >> 4, c = e & 15;      // r: n, c: k
                int gn = bn + r, gk = kb + c;
                float v = (gn < Nn && gk < K) ? B[(size_t)gn * ldb + gk] : 0.f;
                Bs[c][r] = v;
            } else {
                int r = e >> 6, c = e & 63;      // r: k, c: n
                int gk = kb + r, gn = bn + c;
                float v = (gk < K && gn < Nn) ? B[(size_t)gk * ldb + gn] : 0.f;
                Bs[r][c] = v;
            }
        }
        __syncthreads();
        #pragma unroll
        for (int k = 0; k < 16; ++k) {
            float a[4], b[4];
            #pragma unroll
            for (int i = 0; i < 4; ++i) a[i] = As[k][ty * 4 + i];
            #pragma unroll
            for (int j = 0; j < 4; ++j) b[j] = Bs[k][tx * 4 + j];
            #pragma unroll
            for (int i = 0; i < 4; ++i)
                #pragma unroll
                for (int j = 0; j < 4; ++j)
                    acc[i][j] = fmaf(a[i], b[j], acc[i][j]);
        }
        __syncthreads();
    }
    #pragma unroll
    for (int i = 0; i < 4; ++i) {
        int gm = bm + ty * 4 + i;
        if (gm >= M) continue;
        #pragma unroll
        for (int j = 0; j < 4; ++j) {
            int gn = bn + tx * 4 + j;
            if (gn >= Nn) continue;
            float v = alpha * acc[i][j];
            if (SPLITK) {
                if (bias && blockIdx.z == 0) v += bias[gn];
                atomicAdd(&C[(size_t)gm * ldc + gn], v);
            } else {
                if (bias) v += bias[gn];
                if (RELU) v = fmaxf(v, 0.f);
                C[(size_t)gm * ldc + gn] = v;
            }
        }
    }
}

// ---------------------------------------------------------------------------
// GCN degree / normalization / scatter
// ---------------------------------------------------------------------------
__global__ void deg_init_kernel(float* deg) {
    int i = blockIdx.x * 256 + threadIdx.x;
    if (i < N_NODES) deg[i] = 1.0f;   // self-loop weight
}
__global__ void deg_accum_kernel(const int* __restrict__ dst,
                                 const float* __restrict__ w, float* deg) {
    int e = blockIdx.x * 256 + threadIdx.x;
    if (e < E_EDGES) atomicAdd(&deg[dst[e]], w[e]);
}
__global__ void dinv_kernel(float* deg) {
    int i = blockIdx.x * 256 + threadIdx.x;
    if (i < N_NODES) deg[i] = rsqrtf(deg[i]);   // deg >= 1 always
}

// one wave per edge, 64 lanes cover 256 dims as float4
__global__ __launch_bounds__(256)
void scatter_kernel(const int* __restrict__ src, const int* __restrict__ dst,
                    const float* __restrict__ w, const float* __restrict__ dinv,
                    const float* __restrict__ xw, float* __restrict__ hacc) {
    size_t t = (size_t)blockIdx.x * 256 + threadIdx.x;
    int e = (int)(t >> 6);
    if (e >= E_EDGES) return;
    int dq = (int)(t & 63) << 2;
    int s = src[e], d = dst[e];
    float nrm = dinv[s] * w[e] * dinv[d];
    const float4 x4 = *reinterpret_cast<const float4*>(xw + (size_t)s * DM_ + dq);
    float* hr = hacc + (size_t)d * DM_ + dq;
    atomicAdd(hr + 0, nrm * x4.x);
    atomicAdd(hr + 1, nrm * x4.y);
    atomicAdd(hr + 2, nrm * x4.z);
    atomicAdd(hr + 3, nrm * x4.w);
}

// h[n][d] = relu(hacc[n][d] + dinv[n]^2 * xw[n][d] + b[d])   (in place ok)
__global__ __launch_bounds__(256)
void gcn_finalize_kernel(const float* __restrict__ hacc, const float* __restrict__ xw,
                         const float* __restrict__ dinv, const float* __restrict__ b,
                         float* __restrict__ h) {
    int n = blockIdx.x, d = threadIdx.x;
    size_t idx = (size_t)n * DM_ + d;
    float di = dinv[n];
    float v = hacc[idx] + di * di * xw[idx] + b[d];
    h[idx] = fmaxf(v, 0.f);
}

// ---------------------------------------------------------------------------
// Row softmax over 4096 columns, one block (256 thr) per row, 16 vals/thread
// ---------------------------------------------------------------------------
__global__ __launch_bounds__(256)
void softmax_kernel(float* __restrict__ S) {
    float* row = S + (size_t)blockIdx.x * 4096;
    const int tid = threadIdx.x;
    float v[16];
    float m = -3.4e38f;
    #pragma unroll
    for (int i = 0; i < 16; ++i) { v[i] = row[tid + (i << 8)]; m = fmaxf(m, v[i]); }
    #pragma unroll
    for (int off = 32; off; off >>= 1) m = fmaxf(m, __shfl_xor(m, off));
    __shared__ float red[8];
    const int wid = tid >> 6;
    if ((tid & 63) == 0) red[wid] = m;
    __syncthreads();
    m = fmaxf(fmaxf(red[0], red[1]), fmaxf(red[2], red[3]));
    float s = 0.f;
    #pragma unroll
    for (int i = 0; i < 16; ++i) { v[i] = __expf(v[i] - m); s += v[i]; }
    #pragma unroll
    for (int off = 32; off; off >>= 1) s += __shfl_xor(s, off);
    if ((tid & 63) == 0) red[4 + wid] = s;
    __syncthreads();
    s = red[4] + red[5] + red[6] + red[7];
    float inv = 1.f / s;
    #pragma unroll
    for (int i = 0; i < 16; ++i) row[tid + (i << 8)] = v[i] * inv;
}

// ---------------------------------------------------------------------------
// out[n][d] = LN(a[n] + b[n]) * g + beta   (D = 256, one block per row)
// ---------------------------------------------------------------------------
__global__ __launch_bounds__(256)
void ln_kernel(const float* __restrict__ a, const float* __restrict__ b,
               const float* __restrict__ g, const float* __restrict__ be,
               float* __restrict__ out) {
    const int n = blockIdx.x, d = threadIdx.x;
    const size_t idx = (size_t)n * DM_ + d;
    float x = a[idx] + b[idx];
    float s = x;
    #pragma unroll
    for (int off = 32; off; off >>= 1) s += __shfl_xor(s, off);
    __shared__ float red[8];
    const int wid = d >> 6;
    if ((d & 63) == 0) red[wid] = s;
    __syncthreads();
    float mu = (red[0] + red[1] + red[2] + red[3]) * (1.f / 256.f);
    float c = x - mu;
    float q = c * c;
    #pragma unroll
    for (int off = 32; off; off >>= 1) q += __shfl_xor(q, off);
    if ((d & 63) == 0) red[4 + wid] = q;
    __syncthreads();
    float var = (red[4] + red[5] + red[6] + red[7]) * (1.f / 256.f);
    out[idx] = c * rsqrtf(var + EPS_) * g[d] + be[d];
}

// ---------------------------------------------------------------------------
extern "C" void kernel_launch(void* const* d_in, const int* in_sizes, int n_in,
                              void* d_out, int out_size, void* d_ws, size_t ws_size,
                              hipStream_t stream) {
    const float* x   = (const float*)d_in[0];
    const int*   ei  = (const int*)  d_in[1];
    const float* ew  = (const float*)d_in[2];
    const float* Wg  = (const float*)d_in[3];
    const float* bg  = (const float*)d_in[4];
    const float* inw = (const float*)d_in[5];
    const float* inb = (const float*)d_in[6];
    const float* ow  = (const float*)d_in[7];
    const float* ob  = (const float*)d_in[8];
    const float* l1w = (const float*)d_in[9];
    const float* l1b = (const float*)d_in[10];
    const float* l2w = (const float*)d_in[11];
    const float* l2b = (const float*)d_in[12];
    const float* g1  = (const float*)d_in[13];
    const float* b1  = (const float*)d_in[14];
    const float* g2  = (const float*)d_in[15];
    const float* b2  = (const float*)d_in[16];
    float* out = (float*)d_out;

    char* ws = (char*)d_ws;
    size_t off = 0;
    auto alloc = [&](size_t bytes) {
        void* p = ws + off;
        off += (bytes + 255) & ~(size_t)255;
        return p;
    };
    float* deg  = (float*)alloc((size_t)N_NODES * 4);                  // -> dinv
    float* xw   = (float*)alloc((size_t)N_NODES * DM_ * 4);            // 4 MB
    float* h    = (float*)alloc((size_t)N_NODES * DM_ * 4);            // 4 MB
    float* qkv  = (float*)alloc((size_t)N_NODES * 3 * DM_ * 4);        // 12 MB
    float* attn = (float*)alloc((size_t)N_NODES * DM_ * 4);            // 4 MB
    float* tmp  = (float*)alloc((size_t)N_NODES * DM_ * 4);            // 4 MB
    float* h1   = (float*)alloc((size_t)N_NODES * DM_ * 4);            // 4 MB
    float* Sbuf = (float*)alloc((size_t)2048 * 4096 * 4);              // 32 MB
    float* ff1  = Sbuf;  // reused (disjoint lifetimes)
    (void)ws_size; (void)in_sizes; (void)n_in; (void)out_size;

    const int* srcI = ei;
    const int* dstI = ei + E_EDGES;

    // ---- GCN ----
    deg_init_kernel<<<16, 256, 0, stream>>>(deg);
    deg_accum_kernel<<<E_EDGES / 256, 256, 0, stream>>>(dstI, ew, deg);
    dinv_kernel<<<16, 256, 0, stream>>>(deg);
    // xw = x @ W_gcn   (NN: B is [K=512, N=256])
    gemm_kernel<false, false, false><<<dim3(DM_ / 64, N_NODES / 64), 256, 0, stream>>>(
        x, Wg, nullptr, xw, N_NODES, DM_, DIN_, DIN_, DM_, DM_, 1.f, 0);
    hipMemsetAsync(h, 0, (size_t)N_NODES * DM_ * 4, stream);
    scatter_kernel<<<(E_EDGES * 64) / 256, 256, 0, stream>>>(srcI, dstI, ew, deg, xw, h);
    gcn_finalize_kernel<<<N_NODES, 256, 0, stream>>>(h, xw, deg, bg, h);

    // ---- QKV = h @ in_proj_w.T + in_proj_b ----
    gemm_kernel<true, false, false><<<dim3(768 / 64, N_NODES / 64), 256, 0, stream>>>(
        h, inw, inb, qkv, N_NODES, 3 * DM_, DM_, DM_, DM_, 3 * DM_, 1.f, 0);

    // ---- attention: 2 heads, dh=128, 2048-row stripes ----
    hipMemsetAsync(attn, 0, (size_t)N_NODES * DM_ * 4, stream);
    for (int hd = 0; hd < 2; ++hd) {
        for (int s = 0; s < 2; ++s) {
            const float* Q = qkv + (size_t)s * 2048 * 768 + hd * 128;
            const float* Kp = qkv + 256 + hd * 128;
            const float* Vp = qkv + 512 + hd * 128;
            // S = Q K^T / sqrt(128)
            gemm_kernel<true, false, false><<<dim3(64, 32), 256, 0, stream>>>(
                Q, Kp, nullptr, Sbuf, 2048, 4096, 128, 768, 768, 4096,
                0.08838834764831845f, 0);
            softmax_kernel<<<2048, 256, 0, stream>>>(Sbuf);
            // O = P V  (split-K over 4096 keys, atomic accumulate)
            gemm_kernel<false, false, true><<<dim3(2, 32, 8), 256, 0, stream>>>(
                Sbuf, Vp, nullptr, attn + (size_t)s * 2048 * 256 + hd * 128,
                2048, 128, 4096, 4096, 768, 256, 1.f, 512);
        }
    }

    // ---- out_proj -> tmp; h1 = LN(h + tmp) ----
    gemm_kernel<true, false, false><<<dim3(4, 64), 256, 0, stream>>>(
        attn, ow, ob, tmp, N_NODES, DM_, DM_, DM_, DM_, DM_, 1.f, 0);
    ln_kernel<<<N_NODES, 256, 0, stream>>>(h, tmp, g1, b1, h1);

    // ---- FFN ----
    gemm_kernel<true, true, false><<<dim3(DFF_ / 64, N_NODES / 64), 256, 0, stream>>>(
        h1, l1w, l1b, ff1, N_NODES, DFF_, DM_, DM_, DM_, DFF_, 1.f, 0);
    hipMemsetAsync(tmp, 0, (size_t)N_NODES * DM_ * 4, stream);
    gemm_kernel<true, false, true><<<dim3(4, 64, 4), 256, 0, stream>>>(
        ff1, l2w, l2b, tmp, N_NODES, DM_, DFF_, DFF_, DFF_, DM_, 1.f, 512);
    ln_kernel<<<N_NODES, 256, 0, stream>>>(h1, tmp, g2, b2, out);
}

// Round 2
// 1041.320 us; speedup vs baseline: 1.3927x; 1.3927x over previous
//
#include <hip/hip_runtime.h>
#include <hip/hip_bf16.h>

#define N_NODES 4096
#define E_EDGES 131072
#define DIN_    512
#define DM_     256
#define DFF_    2048
#define EPS_    1e-5f

// ---------------------------------------------------------------------------
// Generic fp32 tiled GEMM: C[m,n] = epi(alpha * sum_k A[m,k]*B(k,n) + bias[n])
//   BT=true : B row-major [N,K]  -> B(k,n) = B[n*ldb + k]   (PyTorch W.T style)
//   BT=false: B row-major [K,N]  -> B(k,n) = B[k*ldb + n]
//   SPLITK  : gridDim.z partitions K in chunks of `kchunk`; atomicAdd outputs;
//             bias added only by blockIdx.z==0 (output must be zeroed first).
// Tiles: 64x64, BK=16, 256 threads, 4x4 accum per thread.
// ---------------------------------------------------------------------------
template<bool BT, bool RELU, bool SPLITK>
__global__ __launch_bounds__(256)
void gemm_kernel(const float* __restrict__ A, const float* __restrict__ B,
                 const float* __restrict__ bias, float* __restrict__ C,
                 int M, int Nn, int K, int lda, int ldb, int ldc,
                 float alpha, int kchunk)
{
    __shared__ float As[16][68];
    __shared__ float Bs[16][68];
    const int tid = threadIdx.x;
    const int tx = tid & 15, ty = tid >> 4;
    const int bm = blockIdx.y * 64, bn = blockIdx.x * 64;
    int k0 = 0, k1 = K;
    if (SPLITK) {
        k0 = blockIdx.z * kchunk;
        k1 = k0 + kchunk; if (k1 > K) k1 = K;
    }
    float acc[4][4] = {};
    for (int kb = k0; kb < k1; kb += 16) {
        #pragma unroll
        for (int i = 0; i < 4; ++i) {            // A tile 64x16 -> As[k][m]
            int e = tid + i * 256;
            int r = e >> 4, c = e & 15;
            int gr = bm + r, gc = kb + c;
            float v = (gr < M && gc < K) ? A[(size_t)gr * lda + gc] : 0.f;
            As[c][r] = v;
        }
        #pragma unroll
        for (int i = 0; i < 4; ++i) {            // B tile -> Bs[k][n]
            int e = tid + i * 256;
            if (BT) {
                int r = e >> 4, c = e & 15;      // r: n, c: k
                int gn = bn + r, gk = kb + c;
                float v = (gn < Nn && gk < K) ? B[(size_t)gn * ldb + gk] : 0.f;
                Bs[c][r] = v;
            } else {
                int r = e >> 6, c = e & 63;      // r: k, c: n
                int gk = kb + r, gn = bn + c;
                float v = (gk < K && gn < Nn) ? B[(size_t)gk * ldb + gn] : 0.f;
                Bs[r][c] = v;
            }
        }
        __syncthreads();
        #pragma unroll
        for (int k = 0; k < 16; ++k) {
            float a[4], b[4];
            #pragma unroll
            for (int i = 0; i < 4; ++i) a[i] = As[k][ty * 4 + i];
            #pragma unroll
            for (int j = 0; j < 4; ++j) b[j] = Bs[k][tx * 4 + j];
            #pragma unroll
            for (int i = 0; i < 4; ++i)
                #pragma unroll
                for (int j = 0; j < 4; ++j)
                    acc[i][j] = fmaf(a[i], b[j], acc[i][j]);
        }
        __syncthreads();
    }
    #pragma unroll
    for (int i = 0; i < 4; ++i) {
        int gm = bm + ty * 4 + i;
        if (gm >= M) continue;
        #pragma unroll
        for (int j = 0; j < 4; ++j) {
            int gn = bn + tx * 4 + j;
            if (gn >= Nn) continue;
            float v = alpha * acc[i][j];
            if (SPLITK) {
                if (bias && blockIdx.z == 0) v += bias[gn];
                atomicAdd(&C[(size_t)gm * ldc + gn], v);
            } else {
                if (bias) v += bias[gn];
                if (RELU) v = fmaxf(v, 0.f);
                C[(size_t)gm * ldc + gn] = v;
            }
        }
    }
}

// ---------------------------------------------------------------------------
// GCN: degree, CSR build (dst-bucketed), gather-aggregate
// ---------------------------------------------------------------------------
__global__ void deg_init_kernel(float* deg, int* count) {
    int i = blockIdx.x * 256 + threadIdx.x;
    if (i < N_NODES) { deg[i] = 1.0f; count[i] = 0; }   // self-loop weight
}
__global__ void deg_accum_kernel(const int* __restrict__ dst,
                                 const float* __restrict__ w,
                                 float* deg, int* count) {
    int e = blockIdx.x * 256 + threadIdx.x;
    if (e < E_EDGES) {
        int d = dst[e];
        atomicAdd(&deg[d], w[e]);
        atomicAdd(&count[d], 1);
    }
}
__global__ void dinv_kernel(float* deg) {
    int i = blockIdx.x * 256 + threadIdx.x;
    if (i < N_NODES) deg[i] = rsqrtf(deg[i]);   // deg >= 1 always
}

// exclusive scan of count[4096] -> start[4097]; cursor = start copy
__global__ __launch_bounds__(256)
void csr_scan_kernel(const int* __restrict__ count, int* __restrict__ start,
                     int* __restrict__ cursor) {
    __shared__ int sum[256];
    const int tid = threadIdx.x;
    const int base = tid * 16;
    int loc[16]; int s = 0;
    #pragma unroll
    for (int i = 0; i < 16; ++i) { loc[i] = count[base + i]; s += loc[i]; }
    sum[tid] = s;
    __syncthreads();
    for (int off = 1; off < 256; off <<= 1) {
        int v = (tid >= off) ? sum[tid - off] : 0;
        __syncthreads();
        sum[tid] += v;
        __syncthreads();
    }
    int run = sum[tid] - s;   // exclusive prefix of this thread's chunk
    #pragma unroll
    for (int i = 0; i < 16; ++i) {
        start[base + i] = run;
        cursor[base + i] = run;
        run += loc[i];
    }
    if (tid == 255) start[N_NODES] = run;
}

__global__ void csr_fill_kernel(const int* __restrict__ src, const int* __restrict__ dst,
                                const float* __restrict__ w, const float* __restrict__ dinv,
                                int* __restrict__ cursor,
                                int* __restrict__ csr_src, float* __restrict__ csr_nrm) {
    int e = blockIdx.x * 256 + threadIdx.x;
    if (e >= E_EDGES) return;
    int s = src[e], d = dst[e];
    int pos = atomicAdd(&cursor[d], 1);
    csr_src[pos] = s;
    csr_nrm[pos] = dinv[s] * w[e] * dinv[d];
}

// one block per dst node; thread d owns dim d. Fuses self-loop + bias + ReLU.
__global__ __launch_bounds__(256)
void gcn_gather_kernel(const int* __restrict__ start, const int* __restrict__ csr_src,
                       const float* __restrict__ csr_nrm, const float* __restrict__ xw,
                       const float* __restrict__ dinv, const float* __restrict__ b,
                       float* __restrict__ h) {
    const int n = blockIdx.x, d = threadIdx.x;
    const int s0 = start[n], s1 = start[n + 1];
    float acc = 0.f;
    __shared__ int   ssrc[256];
    __shared__ float snrm[256];
    for (int base = s0; base < s1; base += 256) {
        const int cnt = min(256, s1 - base);
        __syncthreads();
        if (d < cnt) { ssrc[d] = csr_src[base + d]; snrm[d] = csr_nrm[base + d]; }
        __syncthreads();
        for (int j = 0; j < cnt; ++j)
            acc = fmaf(snrm[j], xw[(size_t)ssrc[j] * DM_ + d], acc);
    }
    const float di = dinv[n];
    float v = acc + di * di * xw[(size_t)n * DM_ + d] + b[d];
    h[(size_t)n * DM_ + d] = fmaxf(v, 0.f);
}

// ---------------------------------------------------------------------------
// Row softmax over 4096 columns, one block (256 thr) per row, 16 vals/thread
// ---------------------------------------------------------------------------
__global__ __launch_bounds__(256)
void softmax_kernel(float* __restrict__ S) {
    float* row = S + (size_t)blockIdx.x * 4096;
    const int tid = threadIdx.x;
    float v[16];
    float m = -3.4e38f;
    #pragma unroll
    for (int i = 0; i < 16; ++i) { v[i] = row[tid + (i << 8)]; m = fmaxf(m, v[i]); }
    #pragma unroll
    for (int off = 32; off; off >>= 1) m = fmaxf(m, __shfl_xor(m, off));
    __shared__ float red[8];
    const int wid = tid >> 6;
    if ((tid & 63) == 0) red[wid] = m;
    __syncthreads();
    m = fmaxf(fmaxf(red[0], red[1]), fmaxf(red[2], red[3]));
    float s = 0.f;
    #pragma unroll
    for (int i = 0; i < 16; ++i) { v[i] = __expf(v[i] - m); s += v[i]; }
    #pragma unroll
    for (int off = 32; off; off >>= 1) s += __shfl_xor(s, off);
    if ((tid & 63) == 0) red[4 + wid] = s;
    __syncthreads();
    s = red[4] + red[5] + red[6] + red[7];
    float inv = 1.f / s;
    #pragma unroll
    for (int i = 0; i < 16; ++i) row[tid + (i << 8)] = v[i] * inv;
}

// ---------------------------------------------------------------------------
// out[n][d] = LN(a[n] + b[n]) * g + beta   (D = 256, one block per row)
// ---------------------------------------------------------------------------
__global__ __launch_bounds__(256)
void ln_kernel(const float* __restrict__ a, const float* __restrict__ b,
               const float* __restrict__ g, const float* __restrict__ be,
               float* __restrict__ out) {
    const int n = blockIdx.x, d = threadIdx.x;
    const size_t idx = (size_t)n * DM_ + d;
    float x = a[idx] + b[idx];
    float s = x;
    #pragma unroll
    for (int off = 32; off; off >>= 1) s += __shfl_xor(s, off);
    __shared__ float red[8];
    const int wid = d >> 6;
    if ((d & 63) == 0) red[wid] = s;
    __syncthreads();
    float mu = (red[0] + red[1] + red[2] + red[3]) * (1.f / 256.f);
    float c = x - mu;
    float q = c * c;
    #pragma unroll
    for (int off = 32; off; off >>= 1) q += __shfl_xor(q, off);
    if ((d & 63) == 0) red[4 + wid] = q;
    __syncthreads();
    float var = (red[4] + red[5] + red[6] + red[7]) * (1.f / 256.f);
    out[idx] = c * rsqrtf(var + EPS_) * g[d] + be[d];
}

// ---------------------------------------------------------------------------
extern "C" void kernel_launch(void* const* d_in, const int* in_sizes, int n_in,
                              void* d_out, int out_size, void* d_ws, size_t ws_size,
                              hipStream_t stream) {
    const float* x   = (const float*)d_in[0];
    const int*   ei  = (const int*)  d_in[1];
    const float* ew  = (const float*)d_in[2];
    const float* Wg  = (const float*)d_in[3];
    const float* bg  = (const float*)d_in[4];
    const float* inw = (const float*)d_in[5];
    const float* inb = (const float*)d_in[6];
    const float* ow  = (const float*)d_in[7];
    const float* ob  = (const float*)d_in[8];
    const float* l1w = (const float*)d_in[9];
    const float* l1b = (const float*)d_in[10];
    const float* l2w = (const float*)d_in[11];
    const float* l2b = (const float*)d_in[12];
    const float* g1  = (const float*)d_in[13];
    const float* b1  = (const float*)d_in[14];
    const float* g2  = (const float*)d_in[15];
    const float* b2  = (const float*)d_in[16];
    float* out = (float*)d_out;

    char* ws = (char*)d_ws;
    size_t off = 0;
    auto alloc = [&](size_t bytes) {
        void* p = ws + off;
        off += (bytes + 255) & ~(size_t)255;
        return p;
    };
    float* deg     = (float*)alloc((size_t)N_NODES * 4);               // -> dinv
    int*   count   = (int*)  alloc((size_t)N_NODES * 4);
    int*   startA  = (int*)  alloc((size_t)(N_NODES + 1) * 4);
    int*   cursor  = (int*)  alloc((size_t)N_NODES * 4);
    int*   csr_src = (int*)  alloc((size_t)E_EDGES * 4);
    float* csr_nrm = (float*)alloc((size_t)E_EDGES * 4);
    float* xw   = (float*)alloc((size_t)N_NODES * DM_ * 4);            // 4 MB
    float* h    = (float*)alloc((size_t)N_NODES * DM_ * 4);            // 4 MB
    float* qkv  = (float*)alloc((size_t)N_NODES * 3 * DM_ * 4);        // 12 MB
    float* attn = (float*)alloc((size_t)N_NODES * DM_ * 4);            // 4 MB
    float* tmp  = (float*)alloc((size_t)N_NODES * DM_ * 4);            // 4 MB
    float* h1   = (float*)alloc((size_t)N_NODES * DM_ * 4);            // 4 MB
    float* Sbuf = (float*)alloc((size_t)2048 * 4096 * 4);              // 32 MB
    float* ff1  = Sbuf;  // reused (disjoint lifetimes)
    (void)ws_size; (void)in_sizes; (void)n_in; (void)out_size;

    const int* srcI = ei;
    const int* dstI = ei + E_EDGES;

    // ---- GCN: degrees + CSR build (runs concurrently with xw GEMM deps) ----
    deg_init_kernel<<<16, 256, 0, stream>>>(deg, count);
    deg_accum_kernel<<<E_EDGES / 256, 256, 0, stream>>>(dstI, ew, deg, count);
    dinv_kernel<<<16, 256, 0, stream>>>(deg);
    csr_scan_kernel<<<1, 256, 0, stream>>>(count, startA, cursor);
    csr_fill_kernel<<<E_EDGES / 256, 256, 0, stream>>>(srcI, dstI, ew, deg, cursor,
                                                       csr_src, csr_nrm);
    // xw = x @ W_gcn   (NN: B is [K=512, N=256])
    gemm_kernel<false, false, false><<<dim3(DM_ / 64, N_NODES / 64), 256, 0, stream>>>(
        x, Wg, nullptr, xw, N_NODES, DM_, DIN_, DIN_, DM_, DM_, 1.f, 0);
    // gather-aggregate (fuses self-loop + bias + relu)
    gcn_gather_kernel<<<N_NODES, 256, 0, stream>>>(startA, csr_src, csr_nrm, xw,
                                                   deg, bg, h);

    // ---- QKV = h @ in_proj_w.T + in_proj_b ----
    gemm_kernel<true, false, false><<<dim3(768 / 64, N_NODES / 64), 256, 0, stream>>>(
        h, inw, inb, qkv, N_NODES, 3 * DM_, DM_, DM_, DM_, 3 * DM_, 1.f, 0);

    // ---- attention: 2 heads, dh=128, 2048-row stripes ----
    hipMemsetAsync(attn, 0, (size_t)N_NODES * DM_ * 4, stream);
    for (int hd = 0; hd < 2; ++hd) {
        for (int s = 0; s < 2; ++s) {
            const float* Q = qkv + (size_t)s * 2048 * 768 + hd * 128;
            const float* Kp = qkv + 256 + hd * 128;
            const float* Vp = qkv + 512 + hd * 128;
            // S = Q K^T / sqrt(128)
            gemm_kernel<true, false, false><<<dim3(64, 32), 256, 0, stream>>>(
                Q, Kp, nullptr, Sbuf, 2048, 4096, 128, 768, 768, 4096,
                0.08838834764831845f, 0);
            softmax_kernel<<<2048, 256, 0, stream>>>(Sbuf);
            // O = P V  (split-K over 4096 keys, atomic accumulate)
            gemm_kernel<false, false, true><<<dim3(2, 32, 8), 256, 0, stream>>>(
                Sbuf, Vp, nullptr, attn + (size_t)s * 2048 * 256 + hd * 128,
                2048, 128, 4096, 4096, 768, 256, 1.f, 512);
        }
    }

    // ---- out_proj -> tmp; h1 = LN(h + tmp) ----
    gemm_kernel<true, false, false><<<dim3(4, 64), 256, 0, stream>>>(
        attn, ow, ob, tmp, N_NODES, DM_, DM_, DM_, DM_, DM_, 1.f, 0);
    ln_kernel<<<N_NODES, 256, 0, stream>>>(h, tmp, g1, b1, h1);

    // ---- FFN ----
    gemm_kernel<true, true, false><<<dim3(DFF_ / 64, N_NODES / 64), 256, 0, stream>>>(
        h1, l1w, l1b, ff1, N_NODES, DFF_, DM_, DM_, DM_, DFF_, 1.f, 0);
    hipMemsetAsync(tmp, 0, (size_t)N_NODES * DM_ * 4, stream);
    gemm_kernel<true, false, true><<<dim3(4, 64, 4), 256, 0, stream>>>(
        ff1, l2w, l2b, tmp, N_NODES, DM_, DFF_, DFF_, DFF_, DM_, 1.f, 512);
    ln_kernel<<<N_NODES, 256, 0, stream>>>(h1, tmp, g2, b2, out);
}

// Round 3
// 431.688 us; speedup vs baseline: 3.3595x; 2.4122x over previous
//
#include <hip/hip_runtime.h>
#include <hip/hip_bf16.h>

#define N_NODES 4096
#define E_EDGES 131072
#define DIN_    512
#define DM_     256
#define DFF_    2048
#define EPS_    1e-5f

typedef __attribute__((ext_vector_type(8))) short bf16x8;   // 8 bf16 = 4 VGPR
typedef __attribute__((ext_vector_type(4))) float f32x4;

__device__ __forceinline__ short f2b(float f) {
    union { float f; unsigned u; } x; x.f = f;
    unsigned r = x.u + 0x7fff + ((x.u >> 16) & 1);   // RNE
    return (short)(r >> 16);
}

// ---------------------------------------------------------------------------
// casts
// ---------------------------------------------------------------------------
__global__ __launch_bounds__(256)
void castf2b_kernel(const float* __restrict__ s, short* __restrict__ d, int n4) {
    int i = blockIdx.x * 256 + threadIdx.x;
    if (i >= n4) return;
    float4 v = reinterpret_cast<const float4*>(s)[i];
    union { short s[4]; int2 v; } o;
    o.s[0] = f2b(v.x); o.s[1] = f2b(v.y); o.s[2] = f2b(v.z); o.s[3] = f2b(v.w);
    reinterpret_cast<int2*>(d)[i] = o.v;
}

// W_gcn [512][256] f32 -> WgT [256][512] bf16
__global__ __launch_bounds__(256)
void wgt_kernel(const float* __restrict__ W, short* __restrict__ WT) {
    __shared__ float t[32][33];
    const int tx = threadIdx.x & 31, ty = threadIdx.x >> 5;
    const int bk = blockIdx.x * 32, bn = blockIdx.y * 32;
    #pragma unroll
    for (int i = 0; i < 4; ++i) {
        int r = ty + i * 8;
        t[r][tx] = W[(size_t)(bk + r) * DM_ + bn + tx];
    }
    __syncthreads();
    #pragma unroll
    for (int i = 0; i < 4; ++i) {
        int r = ty + i * 8;
        WT[(size_t)(bn + r) * DIN_ + bk + tx] = f2b(t[tx][r]);
    }
}

// qkv bf16 [4096][768] cols 512..767 -> VT [256][4096] (row d = head*128+dh)
__global__ __launch_bounds__(256)
void vt_kernel(const short* __restrict__ qkv, short* __restrict__ VT) {
    __shared__ short t[32][33];
    const int tx = threadIdx.x & 31, ty = threadIdx.x >> 5;
    const int bn = blockIdx.x * 32, bd = blockIdx.y * 32;
    #pragma unroll
    for (int i = 0; i < 4; ++i) {
        int r = ty + i * 8;
        t[r][tx] = qkv[(size_t)(bn + r) * 768 + 512 + bd + tx];
    }
    __syncthreads();
    #pragma unroll
    for (int i = 0; i < 4; ++i) {
        int r = ty + i * 8;
        VT[(size_t)(bd + r) * N_NODES + bn + tx] = t[tx][r];
    }
}

// ---------------------------------------------------------------------------
// bf16 MFMA GEMM: C = A[M,K] @ B^T  (B given row-major [N,K]) + bias, epi.
// 128x128 tile, 4 waves (each 64x64), BK=32, A staged in LDS (XOR-swizzled
// 16B chunks), B frags read direct from global (L2-resident weights).
// All of M,N multiples of 128; K and kchunk multiples of 32.
// ---------------------------------------------------------------------------
template<bool BF16OUT, bool RELU, bool SPLITK>
__global__ __launch_bounds__(256)
void mgemm_kernel(const short* __restrict__ A, const short* __restrict__ B,
                  const float* __restrict__ bias,
                  float* __restrict__ Cf, short* __restrict__ Cb,
                  int M, int N, int K, int lda, int ldb, int ldc, int kchunk)
{
    __shared__ short As[128 * 32];    // 8 KB
    const int tid = threadIdx.x;
    const int lane = tid & 63, w = tid >> 6;
    const int c = lane & 15, g = lane >> 4;
    const int wm = (w >> 1) * 64, wn = (w & 1) * 64;
    const int bm = blockIdx.y * 128, bn = blockIdx.x * 128;
    int k0 = 0, kend = K;
    if (SPLITK) { k0 = blockIdx.z * kchunk; kend = min(K, k0 + kchunk); }

    const int srow = tid >> 1;               // 0..127
    const int kc0  = (tid & 1) * 2;          // 16B-chunk 0 or 2
    const short* Ag = A + (size_t)(bm + srow) * lda;

    f32x4 acc[4][4] = {};
    for (int kb = k0; kb < kend; kb += 32) {
        #pragma unroll
        for (int i = 0; i < 2; ++i) {
            int kc = kc0 + i;
            bf16x8 v = *reinterpret_cast<const bf16x8*>(Ag + kb + kc * 8);
            int kcs = kc ^ ((srow >> 1) & 3);
            *reinterpret_cast<bf16x8*>(&As[srow * 32 + kcs * 8]) = v;
        }
        __syncthreads();
        bf16x8 bf[4];
        #pragma unroll
        for (int nf = 0; nf < 4; ++nf)
            bf[nf] = *reinterpret_cast<const bf16x8*>(
                B + (size_t)(bn + wn + nf * 16 + c) * ldb + kb + g * 8);
        bf16x8 af[4];
        #pragma unroll
        for (int mf = 0; mf < 4; ++mf) {
            int row = wm + mf * 16 + c;
            int kcs = g ^ ((row >> 1) & 3);
            af[mf] = *reinterpret_cast<const bf16x8*>(&As[row * 32 + kcs * 8]);
        }
        #pragma unroll
        for (int mf = 0; mf < 4; ++mf)
            #pragma unroll
            for (int nf = 0; nf < 4; ++nf)
                acc[mf][nf] = __builtin_amdgcn_mfma_f32_16x16x32_bf16(
                    af[mf], bf[nf], acc[mf][nf], 0, 0, 0);
        __syncthreads();
    }
    // epilogue: C row = bm+wm+mf*16+4g+v, col = bn+wn+nf*16+c
    #pragma unroll
    for (int mf = 0; mf < 4; ++mf) {
        const int row = bm + wm + mf * 16 + g * 4;
        #pragma unroll
        for (int nf = 0; nf < 4; ++nf) {
            const int col = bn + wn + nf * 16 + c;
            float bv = bias ? bias[col] : 0.f;
            #pragma unroll
            for (int v = 0; v < 4; ++v) {
                float val = acc[mf][nf][v];
                size_t o = (size_t)(row + v) * ldc + col;
                if (SPLITK) {
                    if (blockIdx.z == 0) val += bv;
                    atomicAdd(&Cf[o], val);
                } else {
                    val += bv;
                    if (RELU) val = fmaxf(val, 0.f);
                    if (BF16OUT) Cb[o] = f2b(val);
                    else         Cf[o] = val;
                }
            }
        }
    }
}

// ---------------------------------------------------------------------------
// Flash attention: 2 heads, dh=128, N=4096. Block = 32 q-rows x 1 head,
// 2 waves (16 q-rows each). K-tiles of 64 keys. K/V read direct from L2.
// ---------------------------------------------------------------------------
__global__ __launch_bounds__(128)
void fattn_kernel(const short* __restrict__ qkv, const short* __restrict__ VT,
                  short* __restrict__ attnb)
{
    const int w = threadIdx.x >> 6, lane = threadIdx.x & 63;
    const int c = lane & 15, g = lane >> 4;
    const int hd = blockIdx.y;
    const int q0 = blockIdx.x * 32 + w * 16;
    __shared__ short Plds[2][16][88];    // padded: 176B row stride -> 2-way

    const short* Q  = qkv + (size_t)q0 * 768 + hd * 128;
    const short* Kb = qkv + 256 + hd * 128;
    const short* Vt = VT + (size_t)hd * 128 * N_NODES;

    bf16x8 qf[4];
    #pragma unroll
    for (int ks = 0; ks < 4; ++ks)
        qf[ks] = *reinterpret_cast<const bf16x8*>(Q + (size_t)c * 768 + ks * 32 + g * 8);

    f32x4 O[8] = {};
    float m[4]  = {-1e30f, -1e30f, -1e30f, -1e30f};
    float lsum[4] = {};
    const float sc = 0.08838834764831845f;   // 1/sqrt(128)

    for (int kt = 0; kt < 64; ++kt) {
        const int key0 = kt * 64;
        f32x4 S[4] = {};
        #pragma unroll
        for (int nf = 0; nf < 4; ++nf) {
            const short* Kr = Kb + (size_t)(key0 + nf * 16 + c) * 768;
            #pragma unroll
            for (int ks = 0; ks < 4; ++ks) {
                bf16x8 kf = *reinterpret_cast<const bf16x8*>(Kr + ks * 32 + g * 8);
                S[nf] = __builtin_amdgcn_mfma_f32_16x16x32_bf16(qf[ks], kf, S[nf], 0, 0, 0);
            }
        }
        // online softmax; row r = 4g+v, col = nf*16+c
        float sv[4][4];
        float mx[4];
        #pragma unroll
        for (int v = 0; v < 4; ++v) {
            #pragma unroll
            for (int nf = 0; nf < 4; ++nf) sv[nf][v] = S[nf][v] * sc;
            mx[v] = fmaxf(fmaxf(sv[0][v], sv[1][v]), fmaxf(sv[2][v], sv[3][v]));
        }
        #pragma unroll
        for (int off = 1; off <= 8; off <<= 1)
            #pragma unroll
            for (int v = 0; v < 4; ++v) mx[v] = fmaxf(mx[v], __shfl_xor(mx[v], off));
        float scl[4];
        #pragma unroll
        for (int v = 0; v < 4; ++v) {
            float mn = fmaxf(m[v], mx[v]);
            scl[v] = __expf(m[v] - mn);
            m[v] = mn;
        }
        float rs[4] = {};
        #pragma unroll
        for (int nf = 0; nf < 4; ++nf)
            #pragma unroll
            for (int v = 0; v < 4; ++v) {
                float p = __expf(sv[nf][v] - m[v]);
                rs[v] += p;
                Plds[w][4 * g + v][nf * 16 + c] = f2b(p);
            }
        #pragma unroll
        for (int off = 1; off <= 8; off <<= 1)
            #pragma unroll
            for (int v = 0; v < 4; ++v) rs[v] += __shfl_xor(rs[v], off);
        #pragma unroll
        for (int v = 0; v < 4; ++v) lsum[v] = lsum[v] * scl[v] + rs[v];
        #pragma unroll
        for (int nf2 = 0; nf2 < 8; ++nf2)
            #pragma unroll
            for (int v = 0; v < 4; ++v) O[nf2][v] *= scl[v];
        // PV: A-frags from Plds (same wave: compiler orders via lgkmcnt)
        bf16x8 pa[2];
        #pragma unroll
        for (int ks = 0; ks < 2; ++ks)
            pa[ks] = *reinterpret_cast<const bf16x8*>(&Plds[w][c][ks * 32 + g * 8]);
        #pragma unroll
        for (int nf2 = 0; nf2 < 8; ++nf2) {
            const short* Vr = Vt + (size_t)(nf2 * 16 + c) * N_NODES + key0;
            #pragma unroll
            for (int ks = 0; ks < 2; ++ks) {
                bf16x8 vf = *reinterpret_cast<const bf16x8*>(Vr + ks * 32 + g * 8);
                O[nf2] = __builtin_amdgcn_mfma_f32_16x16x32_bf16(pa[ks], vf, O[nf2], 0, 0, 0);
            }
        }
    }
    #pragma unroll
    for (int v = 0; v < 4; ++v) {
        const float rinv = 1.f / lsum[v];
        const size_t rowo = (size_t)(q0 + 4 * g + v) * DM_ + hd * 128;
        #pragma unroll
        for (int nf2 = 0; nf2 < 8; ++nf2)
            attnb[rowo + nf2 * 16 + c] = f2b(O[nf2][v] * rinv);
    }
}

// ---------------------------------------------------------------------------
// GCN: degree, CSR build, gather-aggregate
// ---------------------------------------------------------------------------
__global__ void deg_init_kernel(float* deg, int* count) {
    int i = blockIdx.x * 256 + threadIdx.x;
    if (i < N_NODES) { deg[i] = 1.0f; count[i] = 0; }
}
__global__ void deg_accum_kernel(const int* __restrict__ dst,
                                 const float* __restrict__ w,
                                 float* deg, int* count) {
    int e = blockIdx.x * 256 + threadIdx.x;
    if (e < E_EDGES) {
        int d = dst[e];
        atomicAdd(&deg[d], w[e]);
        atomicAdd(&count[d], 1);
    }
}
__global__ void dinv_kernel(float* deg) {
    int i = blockIdx.x * 256 + threadIdx.x;
    if (i < N_NODES) deg[i] = rsqrtf(deg[i]);
}
__global__ __launch_bounds__(256)
void csr_scan_kernel(const int* __restrict__ count, int* __restrict__ start,
                     int* __restrict__ cursor) {
    __shared__ int sum[256];
    const int tid = threadIdx.x;
    const int base = tid * 16;
    int loc[16]; int s = 0;
    #pragma unroll
    for (int i = 0; i < 16; ++i) { loc[i] = count[base + i]; s += loc[i]; }
    sum[tid] = s;
    __syncthreads();
    for (int off = 1; off < 256; off <<= 1) {
        int v = (tid >= off) ? sum[tid - off] : 0;
        __syncthreads();
        sum[tid] += v;
        __syncthreads();
    }
    int run = sum[tid] - s;
    #pragma unroll
    for (int i = 0; i < 16; ++i) {
        start[base + i] = run;
        cursor[base + i] = run;
        run += loc[i];
    }
    if (tid == 255) start[N_NODES] = run;
}
__global__ void csr_fill_kernel(const int* __restrict__ src, const int* __restrict__ dst,
                                const float* __restrict__ w, const float* __restrict__ dinv,
                                int* __restrict__ cursor,
                                int* __restrict__ csr_src, float* __restrict__ csr_nrm) {
    int e = blockIdx.x * 256 + threadIdx.x;
    if (e >= E_EDGES) return;
    int s = src[e], d = dst[e];
    int pos = atomicAdd(&cursor[d], 1);
    csr_src[pos] = s;
    csr_nrm[pos] = dinv[s] * w[e] * dinv[d];
}
// one block per dst node; fuses self-loop + bias + ReLU; writes f32 + bf16
__global__ __launch_bounds__(256)
void gcn_gather_kernel(const int* __restrict__ start, const int* __restrict__ csr_src,
                       const float* __restrict__ csr_nrm, const float* __restrict__ xw,
                       const float* __restrict__ dinv, const float* __restrict__ b,
                       float* __restrict__ h, short* __restrict__ hb) {
    const int n = blockIdx.x, d = threadIdx.x;
    const int s0 = start[n], s1 = start[n + 1];
    float acc = 0.f;
    __shared__ int   ssrc[256];
    __shared__ float snrm[256];
    for (int base = s0; base < s1; base += 256) {
        const int cnt = min(256, s1 - base);
        __syncthreads();
        if (d < cnt) { ssrc[d] = csr_src[base + d]; snrm[d] = csr_nrm[base + d]; }
        __syncthreads();
        for (int j = 0; j < cnt; ++j)
            acc = fmaf(snrm[j], xw[(size_t)ssrc[j] * DM_ + d], acc);
    }
    const float di = dinv[n];
    float v = acc + di * di * xw[(size_t)n * DM_ + d] + b[d];
    v = fmaxf(v, 0.f);
    h[(size_t)n * DM_ + d] = v;
    hb[(size_t)n * DM_ + d] = f2b(v);
}

// ---------------------------------------------------------------------------
// LayerNorm(a+b); writes f32 (always) and bf16 (if outb != null)
// ---------------------------------------------------------------------------
__global__ __launch_bounds__(256)
void ln_kernel(const float* __restrict__ a, const float* __restrict__ b,
               const float* __restrict__ g, const float* __restrict__ be,
               float* __restrict__ outf, short* __restrict__ outb) {
    const int n = blockIdx.x, d = threadIdx.x;
    const size_t idx = (size_t)n * DM_ + d;
    float x = a[idx] + b[idx];
    float s = x;
    #pragma unroll
    for (int off = 32; off; off >>= 1) s += __shfl_xor(s, off);
    __shared__ float red[8];
    const int wid = d >> 6;
    if ((d & 63) == 0) red[wid] = s;
    __syncthreads();
    float mu = (red[0] + red[1] + red[2] + red[3]) * (1.f / 256.f);
    float c = x - mu;
    float q = c * c;
    #pragma unroll
    for (int off = 32; off; off >>= 1) q += __shfl_xor(q, off);
    if ((d & 63) == 0) red[4 + wid] = q;
    __syncthreads();
    float var = (red[4] + red[5] + red[6] + red[7]) * (1.f / 256.f);
    float v = c * rsqrtf(var + EPS_) * g[d] + be[d];
    outf[idx] = v;
    if (outb) outb[idx] = f2b(v);
}

// ---------------------------------------------------------------------------
extern "C" void kernel_launch(void* const* d_in, const int* in_sizes, int n_in,
                              void* d_out, int out_size, void* d_ws, size_t ws_size,
                              hipStream_t stream) {
    const float* x   = (const float*)d_in[0];
    const int*   ei  = (const int*)  d_in[1];
    const float* ew  = (const float*)d_in[2];
    const float* Wg  = (const float*)d_in[3];
    const float* bg  = (const float*)d_in[4];
    const float* inw = (const float*)d_in[5];
    const float* inb = (const float*)d_in[6];
    const float* ow  = (const float*)d_in[7];
    const float* ob  = (const float*)d_in[8];
    const float* l1w = (const float*)d_in[9];
    const float* l1b = (const float*)d_in[10];
    const float* l2w = (const float*)d_in[11];
    const float* l2b = (const float*)d_in[12];
    const float* g1  = (const float*)d_in[13];
    const float* b1  = (const float*)d_in[14];
    const float* g2  = (const float*)d_in[15];
    const float* b2  = (const float*)d_in[16];
    float* out = (float*)d_out;

    char* ws = (char*)d_ws;
    size_t off = 0;
    auto alloc = [&](size_t bytes) {
        void* p = ws + off;
        off += (bytes + 255) & ~(size_t)255;
        return p;
    };
    float* deg     = (float*)alloc((size_t)N_NODES * 4);
    int*   count   = (int*)  alloc((size_t)N_NODES * 4);
    int*   startA  = (int*)  alloc((size_t)(N_NODES + 1) * 4);
    int*   cursor  = (int*)  alloc((size_t)N_NODES * 4);
    int*   csr_src = (int*)  alloc((size_t)E_EDGES * 4);
    float* csr_nrm = (float*)alloc((size_t)E_EDGES * 4);
    short* xb    = (short*)alloc((size_t)N_NODES * DIN_ * 2);          // 4 MB
    short* WgT   = (short*)alloc((size_t)DM_ * DIN_ * 2);
    short* inwb  = (short*)alloc((size_t)768 * DM_ * 2);
    short* owb   = (short*)alloc((size_t)DM_ * DM_ * 2);
    short* l1wb  = (short*)alloc((size_t)DFF_ * DM_ * 2);
    short* l2wb  = (short*)alloc((size_t)DM_ * DFF_ * 2);
    float* xw    = (float*)alloc((size_t)N_NODES * DM_ * 4);           // 4 MB
    float* h     = (float*)alloc((size_t)N_NODES * DM_ * 4);
    short* hb    = (short*)alloc((size_t)N_NODES * DM_ * 2);
    short* qkvb  = (short*)alloc((size_t)N_NODES * 768 * 2);           // 6 MB
    short* VT    = (short*)alloc((size_t)DM_ * N_NODES * 2);           // 2 MB
    short* attnb = (short*)alloc((size_t)N_NODES * DM_ * 2);
    float* tmp   = (float*)alloc((size_t)N_NODES * DM_ * 4);
    float* h1    = (float*)alloc((size_t)N_NODES * DM_ * 4);
    short* h1b   = (short*)alloc((size_t)N_NODES * DM_ * 2);
    short* ff1b  = (short*)alloc((size_t)N_NODES * DFF_ * 2);          // 16 MB
    (void)ws_size; (void)in_sizes; (void)n_in; (void)out_size;

    const int* srcI = ei;
    const int* dstI = ei + E_EDGES;

    // ---- casts ----
    castf2b_kernel<<<2048, 256, 0, stream>>>(x, xb, N_NODES * DIN_ / 4);
    wgt_kernel<<<dim3(16, 8), 256, 0, stream>>>(Wg, WgT);
    castf2b_kernel<<<192, 256, 0, stream>>>(inw, inwb, 768 * DM_ / 4);
    castf2b_kernel<<<64, 256, 0, stream>>>(ow, owb, DM_ * DM_ / 4);
    castf2b_kernel<<<512, 256, 0, stream>>>(l1w, l1wb, DFF_ * DM_ / 4);
    castf2b_kernel<<<512, 256, 0, stream>>>(l2w, l2wb, DM_ * DFF_ / 4);

    // ---- GCN ----
    deg_init_kernel<<<16, 256, 0, stream>>>(deg, count);
    deg_accum_kernel<<<E_EDGES / 256, 256, 0, stream>>>(dstI, ew, deg, count);
    dinv_kernel<<<16, 256, 0, stream>>>(deg);
    csr_scan_kernel<<<1, 256, 0, stream>>>(count, startA, cursor);
    csr_fill_kernel<<<E_EDGES / 256, 256, 0, stream>>>(srcI, dstI, ew, deg, cursor,
                                                       csr_src, csr_nrm);
    mgemm_kernel<false, false, false><<<dim3(2, 32), 256, 0, stream>>>(
        xb, WgT, nullptr, xw, nullptr, N_NODES, DM_, DIN_, DIN_, DIN_, DM_, 0);
    gcn_gather_kernel<<<N_NODES, 256, 0, stream>>>(startA, csr_src, csr_nrm, xw,
                                                   deg, bg, h, hb);

    // ---- QKV ----
    mgemm_kernel<true, false, false><<<dim3(6, 32), 256, 0, stream>>>(
        hb, inwb, inb, nullptr, qkvb, N_NODES, 768, DM_, DM_, DM_, 768, 0);
    vt_kernel<<<dim3(128, 8), 256, 0, stream>>>(qkvb, VT);

    // ---- flash attention ----
    fattn_kernel<<<dim3(128, 2), 128, 0, stream>>>(qkvb, VT, attnb);

    // ---- out_proj + LN1 ----
    mgemm_kernel<false, false, false><<<dim3(2, 32), 256, 0, stream>>>(
        attnb, owb, ob, tmp, nullptr, N_NODES, DM_, DM_, DM_, DM_, DM_, 0);
    ln_kernel<<<N_NODES, 256, 0, stream>>>(h, tmp, g1, b1, h1, h1b);

    // ---- FFN ----
    mgemm_kernel<true, true, false><<<dim3(16, 32), 256, 0, stream>>>(
        h1b, l1wb, l1b, nullptr, ff1b, N_NODES, DFF_, DM_, DM_, DM_, DFF_, 0);
    hipMemsetAsync(tmp, 0, (size_t)N_NODES * DM_ * 4, stream);
    mgemm_kernel<false, false, true><<<dim3(2, 32, 4), 256, 0, stream>>>(
        ff1b, l2wb, l2b, tmp, nullptr, N_NODES, DM_, DFF_, DFF_, DFF_, DM_, 512);
    ln_kernel<<<N_NODES, 256, 0, stream>>>(h1, tmp, g2, b2, out, nullptr);
}

// Round 4
// 309.546 us; speedup vs baseline: 4.6851x; 1.3946x over previous
//
#include <hip/hip_runtime.h>
#include <hip/hip_bf16.h>

#define N_NODES 4096
#define E_EDGES 131072
#define DIN_    512
#define DM_     256
#define DFF_    2048
#define EPS_    1e-5f
#define NSPLIT  8

typedef __attribute__((ext_vector_type(8))) short bf16x8;   // 8 bf16 = 4 VGPR
typedef __attribute__((ext_vector_type(4))) float f32x4;

__device__ __forceinline__ short f2b(float f) {
    union { float f; unsigned u; } x; x.f = f;
    unsigned r = x.u + 0x7fff + ((x.u >> 16) & 1);   // RNE
    return (short)(r >> 16);
}

// ---------------------------------------------------------------------------
// casts
// ---------------------------------------------------------------------------
__global__ __launch_bounds__(256)
void castf2b_kernel(const float* __restrict__ s, short* __restrict__ d, int n4) {
    int i = blockIdx.x * 256 + threadIdx.x;
    if (i >= n4) return;
    float4 v = reinterpret_cast<const float4*>(s)[i];
    union { short s[4]; int2 v; } o;
    o.s[0] = f2b(v.x); o.s[1] = f2b(v.y); o.s[2] = f2b(v.z); o.s[3] = f2b(v.w);
    reinterpret_cast<int2*>(d)[i] = o.v;
}

// W_gcn [512][256] f32 -> WgT [256][512] bf16
__global__ __launch_bounds__(256)
void wgt_kernel(const float* __restrict__ W, short* __restrict__ WT) {
    __shared__ float t[32][33];
    const int tx = threadIdx.x & 31, ty = threadIdx.x >> 5;
    const int bk = blockIdx.x * 32, bn = blockIdx.y * 32;
    #pragma unroll
    for (int i = 0; i < 4; ++i) {
        int r = ty + i * 8;
        t[r][tx] = W[(size_t)(bk + r) * DM_ + bn + tx];
    }
    __syncthreads();
    #pragma unroll
    for (int i = 0; i < 4; ++i) {
        int r = ty + i * 8;
        WT[(size_t)(bn + r) * DIN_ + bk + tx] = f2b(t[tx][r]);
    }
}

// qkv bf16 [4096][768] cols 512..767 -> VT [256][4096] (row d = head*128+dh)
__global__ __launch_bounds__(256)
void vt_kernel(const short* __restrict__ qkv, short* __restrict__ VT) {
    __shared__ short t[32][33];
    const int tx = threadIdx.x & 31, ty = threadIdx.x >> 5;
    const int bn = blockIdx.x * 32, bd = blockIdx.y * 32;
    #pragma unroll
    for (int i = 0; i < 4; ++i) {
        int r = ty + i * 8;
        t[r][tx] = qkv[(size_t)(bn + r) * 768 + 512 + bd + tx];
    }
    __syncthreads();
    #pragma unroll
    for (int i = 0; i < 4; ++i) {
        int r = ty + i * 8;
        VT[(size_t)(bd + r) * N_NODES + bn + tx] = t[tx][r];
    }
}

// ---------------------------------------------------------------------------
// bf16 MFMA GEMM: C = A[M,K] @ B^T  (B given row-major [N,K]) + bias, epi.
// 128x128 tile, 4 waves (each 64x64), BK=32, A staged in LDS (XOR-swizzled
// 16B chunks), B frags read direct from global (L2-resident weights).
// ---------------------------------------------------------------------------
template<bool BF16OUT, bool RELU, bool SPLITK>
__global__ __launch_bounds__(256)
void mgemm_kernel(const short* __restrict__ A, const short* __restrict__ B,
                  const float* __restrict__ bias,
                  float* __restrict__ Cf, short* __restrict__ Cb,
                  int M, int N, int K, int lda, int ldb, int ldc, int kchunk)
{
    __shared__ short As[128 * 32];    // 8 KB
    const int tid = threadIdx.x;
    const int lane = tid & 63, w = tid >> 6;
    const int c = lane & 15, g = lane >> 4;
    const int wm = (w >> 1) * 64, wn = (w & 1) * 64;
    const int bm = blockIdx.y * 128, bn = blockIdx.x * 128;
    int k0 = 0, kend = K;
    if (SPLITK) { k0 = blockIdx.z * kchunk; kend = min(K, k0 + kchunk); }

    const int srow = tid >> 1;               // 0..127
    const int kc0  = (tid & 1) * 2;          // 16B-chunk 0 or 2
    const short* Ag = A + (size_t)(bm + srow) * lda;

    f32x4 acc[4][4] = {};
    for (int kb = k0; kb < kend; kb += 32) {
        #pragma unroll
        for (int i = 0; i < 2; ++i) {
            int kc = kc0 + i;
            bf16x8 v = *reinterpret_cast<const bf16x8*>(Ag + kb + kc * 8);
            int kcs = kc ^ ((srow >> 1) & 3);
            *reinterpret_cast<bf16x8*>(&As[srow * 32 + kcs * 8]) = v;
        }
        __syncthreads();
        bf16x8 bf[4];
        #pragma unroll
        for (int nf = 0; nf < 4; ++nf)
            bf[nf] = *reinterpret_cast<const bf16x8*>(
                B + (size_t)(bn + wn + nf * 16 + c) * ldb + kb + g * 8);
        bf16x8 af[4];
        #pragma unroll
        for (int mf = 0; mf < 4; ++mf) {
            int row = wm + mf * 16 + c;
            int kcs = g ^ ((row >> 1) & 3);
            af[mf] = *reinterpret_cast<const bf16x8*>(&As[row * 32 + kcs * 8]);
        }
        #pragma unroll
        for (int mf = 0; mf < 4; ++mf)
            #pragma unroll
            for (int nf = 0; nf < 4; ++nf)
                acc[mf][nf] = __builtin_amdgcn_mfma_f32_16x16x32_bf16(
                    af[mf], bf[nf], acc[mf][nf], 0, 0, 0);
        __syncthreads();
    }
    #pragma unroll
    for (int mf = 0; mf < 4; ++mf) {
        const int row = bm + wm + mf * 16 + g * 4;
        #pragma unroll
        for (int nf = 0; nf < 4; ++nf) {
            const int col = bn + wn + nf * 16 + c;
            float bv = bias ? bias[col] : 0.f;
            #pragma unroll
            for (int v = 0; v < 4; ++v) {
                float val = acc[mf][nf][v];
                size_t o = (size_t)(row + v) * ldc + col;
                if (SPLITK) {
                    if (blockIdx.z == 0) val += bv;
                    atomicAdd(&Cf[o], val);
                } else {
                    val += bv;
                    if (RELU) val = fmaxf(val, 0.f);
                    if (BF16OUT) Cb[o] = f2b(val);
                    else         Cf[o] = val;
                }
            }
        }
    }
}

// ---------------------------------------------------------------------------
// Flash attention, KV-split: grid (qtiles, heads, NSPLIT). Block = 32 q-rows,
// 2 waves (16 rows each). Each split covers 512 keys (8 tiles of 64).
// Writes bf16 partial O + f32 (m, l) per row; combined by attn_combine.
// ---------------------------------------------------------------------------
__global__ __launch_bounds__(128)
void fattn_kernel(const short* __restrict__ qkv, const short* __restrict__ VT,
                  short* __restrict__ Opart, float* __restrict__ ml)
{
    const int w = threadIdx.x >> 6, lane = threadIdx.x & 63;
    const int c = lane & 15, g = lane >> 4;
    const int hd = blockIdx.y, sp = blockIdx.z;
    const int q0 = blockIdx.x * 32 + w * 16;
    __shared__ short Plds[2][16][88];    // padded: 176B row stride -> 2-way

    const short* Q  = qkv + (size_t)q0 * 768 + hd * 128;
    const short* Kb = qkv + 256 + hd * 128;
    const short* Vt = VT + (size_t)hd * 128 * N_NODES;

    bf16x8 qf[4];
    #pragma unroll
    for (int ks = 0; ks < 4; ++ks)
        qf[ks] = *reinterpret_cast<const bf16x8*>(Q + (size_t)c * 768 + ks * 32 + g * 8);

    f32x4 O[8] = {};
    float m[4]  = {-1e30f, -1e30f, -1e30f, -1e30f};
    float lsum[4] = {};
    const float sc = 0.08838834764831845f;   // 1/sqrt(128)

    for (int kt = sp * 8; kt < sp * 8 + 8; ++kt) {
        const int key0 = kt * 64;
        f32x4 S[4] = {};
        #pragma unroll
        for (int nf = 0; nf < 4; ++nf) {
            const short* Kr = Kb + (size_t)(key0 + nf * 16 + c) * 768;
            #pragma unroll
            for (int ks = 0; ks < 4; ++ks) {
                bf16x8 kf = *reinterpret_cast<const bf16x8*>(Kr + ks * 32 + g * 8);
                S[nf] = __builtin_amdgcn_mfma_f32_16x16x32_bf16(qf[ks], kf, S[nf], 0, 0, 0);
            }
        }
        // online softmax; row r = 4g+v, col = nf*16+c
        float sv[4][4];
        float mx[4];
        #pragma unroll
        for (int v = 0; v < 4; ++v) {
            #pragma unroll
            for (int nf = 0; nf < 4; ++nf) sv[nf][v] = S[nf][v] * sc;
            mx[v] = fmaxf(fmaxf(sv[0][v], sv[1][v]), fmaxf(sv[2][v], sv[3][v]));
        }
        #pragma unroll
        for (int off = 1; off <= 8; off <<= 1)
            #pragma unroll
            for (int v = 0; v < 4; ++v) mx[v] = fmaxf(mx[v], __shfl_xor(mx[v], off));
        float scl[4];
        #pragma unroll
        for (int v = 0; v < 4; ++v) {
            float mn = fmaxf(m[v], mx[v]);
            scl[v] = __expf(m[v] - mn);
            m[v] = mn;
        }
        float rs[4] = {};
        #pragma unroll
        for (int nf = 0; nf < 4; ++nf)
            #pragma unroll
            for (int v = 0; v < 4; ++v) {
                float p = __expf(sv[nf][v] - m[v]);
                rs[v] += p;
                Plds[w][4 * g + v][nf * 16 + c] = f2b(p);
            }
        #pragma unroll
        for (int off = 1; off <= 8; off <<= 1)
            #pragma unroll
            for (int v = 0; v < 4; ++v) rs[v] += __shfl_xor(rs[v], off);
        #pragma unroll
        for (int v = 0; v < 4; ++v) lsum[v] = lsum[v] * scl[v] + rs[v];
        #pragma unroll
        for (int nf2 = 0; nf2 < 8; ++nf2)
            #pragma unroll
            for (int v = 0; v < 4; ++v) O[nf2][v] *= scl[v];
        bf16x8 pa[2];
        #pragma unroll
        for (int ks = 0; ks < 2; ++ks)
            pa[ks] = *reinterpret_cast<const bf16x8*>(&Plds[w][c][ks * 32 + g * 8]);
        #pragma unroll
        for (int nf2 = 0; nf2 < 8; ++nf2) {
            const short* Vr = Vt + (size_t)(nf2 * 16 + c) * N_NODES + key0;
            #pragma unroll
            for (int ks = 0; ks < 2; ++ks) {
                bf16x8 vf = *reinterpret_cast<const bf16x8*>(Vr + ks * 32 + g * 8);
                O[nf2] = __builtin_amdgcn_mfma_f32_16x16x32_bf16(pa[ks], vf, O[nf2], 0, 0, 0);
            }
        }
    }
    // write partials: Opart[((hd*NSPLIT+sp)*4096 + row)*128 + dh], ml[...*2]
    const size_t pbase = ((size_t)hd * NSPLIT + sp) * N_NODES;
    #pragma unroll
    for (int v = 0; v < 4; ++v) {
        const int row = q0 + 4 * g + v;
        const size_t rowo = (pbase + row) * 128;
        #pragma unroll
        for (int nf2 = 0; nf2 < 8; ++nf2)
            Opart[rowo + nf2 * 16 + c] = f2b(O[nf2][v]);
        if (c == 0) {
            ml[(pbase + row) * 2 + 0] = m[v];
            ml[(pbase + row) * 2 + 1] = lsum[v];
        }
    }
}

// combine NSPLIT partials -> attnb bf16 [4096][256]; grid (4096, 2), 128 thr
__global__ __launch_bounds__(128)
void attn_combine_kernel(const short* __restrict__ Opart, const float* __restrict__ ml,
                         short* __restrict__ attnb)
{
    const int row = blockIdx.x, hd = blockIdx.y, d = threadIdx.x;
    float ms[NSPLIT], ls[NSPLIT];
    float mmax = -1e30f;
    #pragma unroll
    for (int s = 0; s < NSPLIT; ++s) {
        const size_t p = ((size_t)hd * NSPLIT + s) * N_NODES + row;
        ms[s] = ml[p * 2 + 0];
        ls[s] = ml[p * 2 + 1];
        mmax = fmaxf(mmax, ms[s]);
    }
    float lt = 0.f, acc = 0.f;
    #pragma unroll
    for (int s = 0; s < NSPLIT; ++s) {
        const float wgt = __expf(ms[s] - mmax);
        lt += wgt * ls[s];
        const size_t p = ((size_t)hd * NSPLIT + s) * N_NODES + row;
        union { short s; unsigned short u; } b; b.s = Opart[p * 128 + d];
        union { unsigned u; float f; } cv; cv.u = ((unsigned)b.u) << 16;
        acc += wgt * cv.f;
    }
    attnb[(size_t)row * DM_ + hd * 128 + d] = f2b(acc / lt);
}

// ---------------------------------------------------------------------------
// GCN: degree, CSR build, gather-aggregate
// ---------------------------------------------------------------------------
__global__ void deg_init_kernel(float* deg, int* count) {
    int i = blockIdx.x * 256 + threadIdx.x;
    if (i < N_NODES) { deg[i] = 1.0f; count[i] = 0; }
}
__global__ void deg_accum_kernel(const int* __restrict__ dst,
                                 const float* __restrict__ w,
                                 float* deg, int* count) {
    int e = blockIdx.x * 256 + threadIdx.x;
    if (e < E_EDGES) {
        int d = dst[e];
        atomicAdd(&deg[d], w[e]);
        atomicAdd(&count[d], 1);
    }
}
__global__ void dinv_kernel(float* deg) {
    int i = blockIdx.x * 256 + threadIdx.x;
    if (i < N_NODES) deg[i] = rsqrtf(deg[i]);
}
__global__ __launch_bounds__(256)
void csr_scan_kernel(const int* __restrict__ count, int* __restrict__ start,
                     int* __restrict__ cursor) {
    __shared__ int sum[256];
    const int tid = threadIdx.x;
    const int base = tid * 16;
    int loc[16]; int s = 0;
    #pragma unroll
    for (int i = 0; i < 16; ++i) { loc[i] = count[base + i]; s += loc[i]; }
    sum[tid] = s;
    __syncthreads();
    for (int off = 1; off < 256; off <<= 1) {
        int v = (tid >= off) ? sum[tid - off] : 0;
        __syncthreads();
        sum[tid] += v;
        __syncthreads();
    }
    int run = sum[tid] - s;
    #pragma unroll
    for (int i = 0; i < 16; ++i) {
        start[base + i] = run;
        cursor[base + i] = run;
        run += loc[i];
    }
    if (tid == 255) start[N_NODES] = run;
}
__global__ void csr_fill_kernel(const int* __restrict__ src, const int* __restrict__ dst,
                                const float* __restrict__ w, const float* __restrict__ dinv,
                                int* __restrict__ cursor,
                                int* __restrict__ csr_src, float* __restrict__ csr_nrm) {
    int e = blockIdx.x * 256 + threadIdx.x;
    if (e >= E_EDGES) return;
    int s = src[e], d = dst[e];
    int pos = atomicAdd(&cursor[d], 1);
    csr_src[pos] = s;
    csr_nrm[pos] = dinv[s] * w[e] * dinv[d];
}
// one block per dst node; fuses self-loop + bias + ReLU; writes f32 + bf16
__global__ __launch_bounds__(256)
void gcn_gather_kernel(const int* __restrict__ start, const int* __restrict__ csr_src,
                       const float* __restrict__ csr_nrm, const float* __restrict__ xw,
                       const float* __restrict__ dinv, const float* __restrict__ b,
                       float* __restrict__ h, short* __restrict__ hb) {
    const int n = blockIdx.x, d = threadIdx.x;
    const int s0 = start[n], s1 = start[n + 1];
    float acc = 0.f;
    __shared__ int   ssrc[256];
    __shared__ float snrm[256];
    for (int base = s0; base < s1; base += 256) {
        const int cnt = min(256, s1 - base);
        __syncthreads();
        if (d < cnt) { ssrc[d] = csr_src[base + d]; snrm[d] = csr_nrm[base + d]; }
        __syncthreads();
        for (int j = 0; j < cnt; ++j)
            acc = fmaf(snrm[j], xw[(size_t)ssrc[j] * DM_ + d], acc);
    }
    const float di = dinv[n];
    float v = acc + di * di * xw[(size_t)n * DM_ + d] + b[d];
    v = fmaxf(v, 0.f);
    h[(size_t)n * DM_ + d] = v;
    hb[(size_t)n * DM_ + d] = f2b(v);
}

// ---------------------------------------------------------------------------
// LayerNorm(a+b); writes f32 (always) and bf16 (if outb != null)
// ---------------------------------------------------------------------------
__global__ __launch_bounds__(256)
void ln_kernel(const float* __restrict__ a, const float* __restrict__ b,
               const float* __restrict__ g, const float* __restrict__ be,
               float* __restrict__ outf, short* __restrict__ outb) {
    const int n = blockIdx.x, d = threadIdx.x;
    const size_t idx = (size_t)n * DM_ + d;
    float x = a[idx] + b[idx];
    float s = x;
    #pragma unroll
    for (int off = 32; off; off >>= 1) s += __shfl_xor(s, off);
    __shared__ float red[8];
    const int wid = d >> 6;
    if ((d & 63) == 0) red[wid] = s;
    __syncthreads();
    float mu = (red[0] + red[1] + red[2] + red[3]) * (1.f / 256.f);
    float c = x - mu;
    float q = c * c;
    #pragma unroll
    for (int off = 32; off; off >>= 1) q += __shfl_xor(q, off);
    if ((d & 63) == 0) red[4 + wid] = q;
    __syncthreads();
    float var = (red[4] + red[5] + red[6] + red[7]) * (1.f / 256.f);
    float v = c * rsqrtf(var + EPS_) * g[d] + be[d];
    outf[idx] = v;
    if (outb) outb[idx] = f2b(v);
}

// ---------------------------------------------------------------------------
extern "C" void kernel_launch(void* const* d_in, const int* in_sizes, int n_in,
                              void* d_out, int out_size, void* d_ws, size_t ws_size,
                              hipStream_t stream) {
    const float* x   = (const float*)d_in[0];
    const int*   ei  = (const int*)  d_in[1];
    const float* ew  = (const float*)d_in[2];
    const float* Wg  = (const float*)d_in[3];
    const float* bg  = (const float*)d_in[4];
    const float* inw = (const float*)d_in[5];
    const float* inb = (const float*)d_in[6];
    const float* ow  = (const float*)d_in[7];
    const float* ob  = (const float*)d_in[8];
    const float* l1w = (const float*)d_in[9];
    const float* l1b = (const float*)d_in[10];
    const float* l2w = (const float*)d_in[11];
    const float* l2b = (const float*)d_in[12];
    const float* g1  = (const float*)d_in[13];
    const float* b1  = (const float*)d_in[14];
    const float* g2  = (const float*)d_in[15];
    const float* b2  = (const float*)d_in[16];
    float* out = (float*)d_out;

    char* ws = (char*)d_ws;
    size_t off = 0;
    auto alloc = [&](size_t bytes) {
        void* p = ws + off;
        off += (bytes + 255) & ~(size_t)255;
        return p;
    };
    float* deg     = (float*)alloc((size_t)N_NODES * 4);
    int*   count   = (int*)  alloc((size_t)N_NODES * 4);
    int*   startA  = (int*)  alloc((size_t)(N_NODES + 1) * 4);
    int*   cursor  = (int*)  alloc((size_t)N_NODES * 4);
    int*   csr_src = (int*)  alloc((size_t)E_EDGES * 4);
    float* csr_nrm = (float*)alloc((size_t)E_EDGES * 4);
    short* xb    = (short*)alloc((size_t)N_NODES * DIN_ * 2);          // 4 MB
    short* WgT   = (short*)alloc((size_t)DM_ * DIN_ * 2);
    short* inwb  = (short*)alloc((size_t)768 * DM_ * 2);
    short* owb   = (short*)alloc((size_t)DM_ * DM_ * 2);
    short* l1wb  = (short*)alloc((size_t)DFF_ * DM_ * 2);
    short* l2wb  = (short*)alloc((size_t)DM_ * DFF_ * 2);
    float* xw    = (float*)alloc((size_t)N_NODES * DM_ * 4);           // 4 MB
    float* h     = (float*)alloc((size_t)N_NODES * DM_ * 4);
    short* hb    = (short*)alloc((size_t)N_NODES * DM_ * 2);
    short* qkvb  = (short*)alloc((size_t)N_NODES * 768 * 2);           // 6 MB
    short* VT    = (short*)alloc((size_t)DM_ * N_NODES * 2);           // 2 MB
    short* attnb = (short*)alloc((size_t)N_NODES * DM_ * 2);
    float* tmp   = (float*)alloc((size_t)N_NODES * DM_ * 4);
    float* h1    = (float*)alloc((size_t)N_NODES * DM_ * 4);
    short* h1b   = (short*)alloc((size_t)N_NODES * DM_ * 2);
    // shared region: {Opart bf16 + ml f32} during attention, ff1b during FFN
    size_t opart_b = (size_t)2 * NSPLIT * N_NODES * 128 * 2;           // 16.8 MB
    size_t ml_b    = (size_t)2 * NSPLIT * N_NODES * 2 * 4;             // 0.5 MB
    size_t ff1_b   = (size_t)N_NODES * DFF_ * 2;                       // 16 MB
    char*  R     = (char*)alloc(opart_b + ml_b > ff1_b ? opart_b + ml_b : ff1_b);
    short* Opart = (short*)R;
    float* ml    = (float*)(R + opart_b);
    short* ff1b  = (short*)R;
    (void)ws_size; (void)in_sizes; (void)n_in; (void)out_size;

    const int* srcI = ei;
    const int* dstI = ei + E_EDGES;

    // ---- casts ----
    castf2b_kernel<<<2048, 256, 0, stream>>>(x, xb, N_NODES * DIN_ / 4);
    wgt_kernel<<<dim3(16, 8), 256, 0, stream>>>(Wg, WgT);
    castf2b_kernel<<<192, 256, 0, stream>>>(inw, inwb, 768 * DM_ / 4);
    castf2b_kernel<<<64, 256, 0, stream>>>(ow, owb, DM_ * DM_ / 4);
    castf2b_kernel<<<512, 256, 0, stream>>>(l1w, l1wb, DFF_ * DM_ / 4);
    castf2b_kernel<<<512, 256, 0, stream>>>(l2w, l2wb, DM_ * DFF_ / 4);

    // ---- GCN ----
    deg_init_kernel<<<16, 256, 0, stream>>>(deg, count);
    deg_accum_kernel<<<E_EDGES / 256, 256, 0, stream>>>(dstI, ew, deg, count);
    dinv_kernel<<<16, 256, 0, stream>>>(deg);
    csr_scan_kernel<<<1, 256, 0, stream>>>(count, startA, cursor);
    csr_fill_kernel<<<E_EDGES / 256, 256, 0, stream>>>(srcI, dstI, ew, deg, cursor,
                                                       csr_src, csr_nrm);
    mgemm_kernel<false, false, false><<<dim3(2, 32), 256, 0, stream>>>(
        xb, WgT, nullptr, xw, nullptr, N_NODES, DM_, DIN_, DIN_, DIN_, DM_, 0);
    gcn_gather_kernel<<<N_NODES, 256, 0, stream>>>(startA, csr_src, csr_nrm, xw,
                                                   deg, bg, h, hb);

    // ---- QKV ----
    mgemm_kernel<true, false, false><<<dim3(6, 32), 256, 0, stream>>>(
        hb, inwb, inb, nullptr, qkvb, N_NODES, 768, DM_, DM_, DM_, 768, 0);
    vt_kernel<<<dim3(128, 8), 256, 0, stream>>>(qkvb, VT);

    // ---- flash attention (KV-split) + combine ----
    fattn_kernel<<<dim3(128, 2, NSPLIT), 128, 0, stream>>>(qkvb, VT, Opart, ml);
    attn_combine_kernel<<<dim3(N_NODES, 2), 128, 0, stream>>>(Opart, ml, attnb);

    // ---- out_proj + LN1 ----
    mgemm_kernel<false, false, false><<<dim3(2, 32), 256, 0, stream>>>(
        attnb, owb, ob, tmp, nullptr, N_NODES, DM_, DM_, DM_, DM_, DM_, 0);
    ln_kernel<<<N_NODES, 256, 0, stream>>>(h, tmp, g1, b1, h1, h1b);

    // ---- FFN ----
    mgemm_kernel<true, true, false><<<dim3(16, 32), 256, 0, stream>>>(
        h1b, l1wb, l1b, nullptr, ff1b, N_NODES, DFF_, DM_, DM_, DM_, DFF_, 0);
    hipMemsetAsync(tmp, 0, (size_t)N_NODES * DM_ * 4, stream);
    mgemm_kernel<false, false, true><<<dim3(2, 32, 4), 256, 0, stream>>>(
        ff1b, l2wb, l2b, tmp, nullptr, N_NODES, DM_, DFF_, DFF_, DFF_, DM_, 512);
    ln_kernel<<<N_NODES, 256, 0, stream>>>(h1, tmp, g2, b2, out, nullptr);
}